// Round 1
// baseline (2811.930 us; speedup 1.0000x reference)
//
#include <hip/hip_runtime.h>

#define BN 8192
#define LOGB 13

__device__ __forceinline__ float tanh_fast(float x) {
  x = fminf(fmaxf(x, -15.f), 15.f);
  float t = __expf(2.f * x);
  return (t - 1.f) / (t + 1.f);
}

// dst layout [Cpad][R]; dst[c][r] = (c<C) ? src[r][c] : 0
__global__ __launch_bounds__(256) void k_transpose_pad(
    const float* __restrict__ src, float* __restrict__ dst, int R, int C, int Cpad) {
  int i = blockIdx.x * 256 + threadIdx.x;
  if (i >= Cpad * R) return;
  int c = i / R, r = i - c * R;
  dst[i] = (c < C) ? src[r * C + c] : 0.f;
}

// ---------------- bottom-up CriticUp: 32 rows/block, 256 threads ----------------
__global__ __launch_bounds__(256, 2) void k_up(
    const float* __restrict__ x, const float* __restrict__ u,
    const float* __restrict__ w1T, const float* __restrict__ b1,   // [33][64]
    const float* __restrict__ w2T, const float* __restrict__ b2,   // [128][64]
    const float* __restrict__ w3T, const float* __restrict__ b3,   // [64][32]
    float* __restrict__ msg_up, int node_base, int has_children) {
  __shared__ float Xs[32][34];
  __shared__ float Hs[32][128];
  __shared__ float H2s[32][64];
  const int tid = threadIdx.x;
  const int r0 = blockIdx.x * 32;

  for (int f = tid; f < 32 * 33; f += 256) {
    int r = f / 33, c = f - r * 33;
    int g = r0 + r;
    int node = node_base + (g >> LOGB), b = g & (BN - 1);
    int rb = (node << LOGB) + b;
    Xs[r][c] = (c < 32) ? x[rb * 32 + c] : u[rb];
  }
  for (int f = tid; f < 32 * 64; f += 256) {
    int r = f >> 6, c = f & 63;
    float v = 0.f;
    if (has_children) {
      int g = r0 + r;
      int node = node_base + (g >> LOGB), b = g & (BN - 1);
      int child = 2 * node + 1 + (c >> 5);
      v = msg_up[((child << LOGB) + b) * 32 + (c & 31)];
    }
    Hs[r][64 + c] = tanh_fast(v);
  }
  __syncthreads();

  const int j = tid & 63, w = tid >> 6;
  float acc[8];
#pragma unroll
  for (int i = 0; i < 8; i++) acc[i] = 0.f;
  for (int k = 0; k < 33; k++) {
    float wv = w1T[k * 64 + j];
#pragma unroll
    for (int i = 0; i < 8; i++) acc[i] = fmaf(wv, Xs[w * 8 + i][k], acc[i]);
  }
  {
    float bj = b1[j];
#pragma unroll
    for (int i = 0; i < 8; i++) {
      float v = acc[i] + bj;
      float ss = v * v;
#pragma unroll
      for (int off = 32; off; off >>= 1) ss += __shfl_xor(ss, off, 64);
      float inv = 1.f / fmaxf(sqrtf(ss), 1e-12f);
      Hs[w * 8 + i][j] = tanh_fast(v * inv);
    }
  }
  __syncthreads();

#pragma unroll
  for (int i = 0; i < 8; i++) acc[i] = 0.f;
  for (int k = 0; k < 128; k++) {
    float wv = w2T[k * 64 + j];
#pragma unroll
    for (int i = 0; i < 8; i++) acc[i] = fmaf(wv, Hs[w * 8 + i][k], acc[i]);
  }
  {
    float b2j = b2[j];
#pragma unroll
    for (int i = 0; i < 8; i++) H2s[w * 8 + i][j] = tanh_fast(acc[i] + b2j);
  }
  __syncthreads();

  const int o = tid & 31, rg = tid >> 5;
  float a3[4];
#pragma unroll
  for (int i = 0; i < 4; i++) a3[i] = 0.f;
  for (int k = 0; k < 64; k++) {
    float wv = w3T[k * 32 + o];
#pragma unroll
    for (int i = 0; i < 4; i++) a3[i] = fmaf(wv, H2s[rg * 4 + i][k], a3[i]);
  }
  {
    float b3o = b3[o];
#pragma unroll
    for (int i = 0; i < 4; i++) {
      float v = a3[i] + b3o;
      float ss = v * v;
#pragma unroll
      for (int off = 16; off; off >>= 1) ss += __shfl_xor(ss, off, 32);
      float inv = 1.f / fmaxf(sqrtf(ss), 1e-12f);
      int g = r0 + rg * 4 + i;
      int node = node_base + (g >> LOGB), b = g & (BN - 1);
      msg_up[((node << LOGB) + b) * 32 + o] = v * inv;
    }
  }
}

// ---------------- top-down Q MLP (q1 or q2): 32 rows/block ----------------
__global__ __launch_bounds__(256, 2) void k_down_q(
    const float* __restrict__ msg_up, const float* __restrict__ u,
    const float* __restrict__ msg_in,
    const float* __restrict__ w1T, const float* __restrict__ b1,   // [68][400]
    const float* __restrict__ w2T, const float* __restrict__ b2,   // [400][300]
    const float* __restrict__ w3, const float* __restrict__ b3,    // [300],[1]
    float* __restrict__ out, int node_base, int has_parent, int zsel) {
  __shared__ __align__(16) float Xs[32][68];
  __shared__ __align__(16) float H1s[32 * 400];
  __shared__ float Red[4][32];
  const int tid = threadIdx.x;
  const int r0 = blockIdx.x * 32;

  for (int f = tid; f < 32 * 68; f += 256) {
    int r = f / 68, c = f - r * 68;
    float v = 0.f;
    if (c < 65) {
      int g = r0 + r;
      int node = node_base + (g >> LOGB), b = g & (BN - 1);
      int rb = (node << LOGB) + b;
      if (c < 32) v = msg_up[rb * 32 + c];
      else if (c == 32) v = u[rb];
      else v = has_parent ? msg_in[rb * 32 + (c - 33)] : 0.f;
    }
    Xs[r][c] = v;
  }
  __syncthreads();

  const int j0 = tid, j1 = tid + 256;
  const bool p1 = (j1 < 400);
  float acc0[32], acc1[32];
#pragma unroll
  for (int r = 0; r < 32; r++) { acc0[r] = 0.f; acc1[r] = 0.f; }

  for (int k4 = 0; k4 < 17; k4++) {
    float w0[4], w1v[4];
#pragma unroll
    for (int kk = 0; kk < 4; kk++) {
      w0[kk] = w1T[(k4 * 4 + kk) * 400 + j0];
      w1v[kk] = p1 ? w1T[(k4 * 4 + kk) * 400 + j1] : 0.f;
    }
#pragma unroll
    for (int r = 0; r < 32; r++) {
      float4 xv = *(const float4*)&Xs[r][k4 * 4];
      acc0[r] = fmaf(w0[0], xv.x, acc0[r]);
      acc0[r] = fmaf(w0[1], xv.y, acc0[r]);
      acc0[r] = fmaf(w0[2], xv.z, acc0[r]);
      acc0[r] = fmaf(w0[3], xv.w, acc0[r]);
      acc1[r] = fmaf(w1v[0], xv.x, acc1[r]);
      acc1[r] = fmaf(w1v[1], xv.y, acc1[r]);
      acc1[r] = fmaf(w1v[2], xv.z, acc1[r]);
      acc1[r] = fmaf(w1v[3], xv.w, acc1[r]);
    }
  }
  {
    float bb0 = b1[j0];
    float bb1 = p1 ? b1[j1] : 0.f;
#pragma unroll
    for (int r = 0; r < 32; r++) {
      H1s[r * 400 + j0] = fmaxf(acc0[r] + bb0, 0.f);
      if (p1) H1s[r * 400 + j1] = fmaxf(acc1[r] + bb1, 0.f);
    }
  }
  __syncthreads();

  const bool p2 = (j1 < 300);
#pragma unroll
  for (int r = 0; r < 32; r++) { acc0[r] = 0.f; acc1[r] = 0.f; }
  for (int k4 = 0; k4 < 100; k4++) {
    float w0[4], w1v[4];
#pragma unroll
    for (int kk = 0; kk < 4; kk++) {
      w0[kk] = w2T[(k4 * 4 + kk) * 300 + j0];
      w1v[kk] = p2 ? w2T[(k4 * 4 + kk) * 300 + j1] : 0.f;
    }
#pragma unroll
    for (int r = 0; r < 32; r++) {
      float4 hv = *(const float4*)&H1s[r * 400 + k4 * 4];
      acc0[r] = fmaf(w0[0], hv.x, acc0[r]);
      acc0[r] = fmaf(w0[1], hv.y, acc0[r]);
      acc0[r] = fmaf(w0[2], hv.z, acc0[r]);
      acc0[r] = fmaf(w0[3], hv.w, acc0[r]);
      acc1[r] = fmaf(w1v[0], hv.x, acc1[r]);
      acc1[r] = fmaf(w1v[1], hv.y, acc1[r]);
      acc1[r] = fmaf(w1v[2], hv.z, acc1[r]);
      acc1[r] = fmaf(w1v[3], hv.w, acc1[r]);
    }
  }
  {
    float bb0 = b2[j0];
    float bb1 = p2 ? b2[j1] : 0.f;
    float wq0 = w3[j0];
    float wq1 = p2 ? w3[j1] : 0.f;
#pragma unroll
    for (int r = 0; r < 32; r++) {
      float h0 = fmaxf(acc0[r] + bb0, 0.f);
      float h1 = fmaxf(acc1[r] + bb1, 0.f);
      float p = fmaf(wq0, h0, wq1 * h1);
#pragma unroll
      for (int off = 32; off; off >>= 1) p += __shfl_xor(p, off, 64);
      if ((tid & 63) == 0) Red[tid >> 6][r] = p;
    }
  }
  __syncthreads();
  if (tid < 32) {
    int g = r0 + tid;
    float q = Red[0][tid] + Red[1][tid] + Red[2][tid] + Red[3][tid] + b3[0];
    out[((node_base << LOGB) + g) * 2 + zsel] = q;
  }
}

// ---------------- top-down message MLP: 16 rows/block ----------------
__global__ __launch_bounds__(256, 2) void k_down_mb(
    const float* __restrict__ msg_up, const float* __restrict__ msg_in,
    const float* __restrict__ w1T, const float* __restrict__ b1,   // [64][400]
    const float* __restrict__ w2T, const float* __restrict__ b2,   // [400][300]
    const float* __restrict__ w3T, const float* __restrict__ b3,   // [300][64],[64]
    float* __restrict__ msg_in_out, int node_base, int has_parent) {
  __shared__ __align__(16) float Xs[16][64];
  __shared__ __align__(16) float H1s[16 * 400];
  __shared__ __align__(16) float H2s[16 * 304];
  const int tid = threadIdx.x;
  const int r0 = blockIdx.x * 16;

  for (int f = tid; f < 16 * 64; f += 256) {
    int r = f >> 6, c = f & 63;
    int g = r0 + r;
    int node = node_base + (g >> LOGB), b = g & (BN - 1);
    int rb = (node << LOGB) + b;
    float v = (c < 32) ? msg_up[rb * 32 + c]
                       : (has_parent ? msg_in[rb * 32 + (c - 32)] : 0.f);
    Xs[r][c] = tanh_fast(v);
  }
  __syncthreads();

  const int j0 = tid, j1 = tid + 256;
  const bool p1 = (j1 < 400);
  float acc0[16], acc1[16];
#pragma unroll
  for (int r = 0; r < 16; r++) { acc0[r] = 0.f; acc1[r] = 0.f; }

  for (int k4 = 0; k4 < 16; k4++) {
    float w0[4], w1v[4];
#pragma unroll
    for (int kk = 0; kk < 4; kk++) {
      w0[kk] = w1T[(k4 * 4 + kk) * 400 + j0];
      w1v[kk] = p1 ? w1T[(k4 * 4 + kk) * 400 + j1] : 0.f;
    }
#pragma unroll
    for (int r = 0; r < 16; r++) {
      float4 xv = *(const float4*)&Xs[r][k4 * 4];
      acc0[r] = fmaf(w0[0], xv.x, acc0[r]);
      acc0[r] = fmaf(w0[1], xv.y, acc0[r]);
      acc0[r] = fmaf(w0[2], xv.z, acc0[r]);
      acc0[r] = fmaf(w0[3], xv.w, acc0[r]);
      acc1[r] = fmaf(w1v[0], xv.x, acc1[r]);
      acc1[r] = fmaf(w1v[1], xv.y, acc1[r]);
      acc1[r] = fmaf(w1v[2], xv.z, acc1[r]);
      acc1[r] = fmaf(w1v[3], xv.w, acc1[r]);
    }
  }
  {
    float bb0 = b1[j0];
    float bb1 = p1 ? b1[j1] : 0.f;
#pragma unroll
    for (int r = 0; r < 16; r++) {
      H1s[r * 400 + j0] = fmaxf(acc0[r] + bb0, 0.f);
      if (p1) H1s[r * 400 + j1] = fmaxf(acc1[r] + bb1, 0.f);
    }
  }
  __syncthreads();

  const bool p2 = (j1 < 300);
#pragma unroll
  for (int r = 0; r < 16; r++) { acc0[r] = 0.f; acc1[r] = 0.f; }
  for (int k4 = 0; k4 < 100; k4++) {
    float w0[4], w1v[4];
#pragma unroll
    for (int kk = 0; kk < 4; kk++) {
      w0[kk] = w2T[(k4 * 4 + kk) * 300 + j0];
      w1v[kk] = p2 ? w2T[(k4 * 4 + kk) * 300 + j1] : 0.f;
    }
#pragma unroll
    for (int r = 0; r < 16; r++) {
      float4 hv = *(const float4*)&H1s[r * 400 + k4 * 4];
      acc0[r] = fmaf(w0[0], hv.x, acc0[r]);
      acc0[r] = fmaf(w0[1], hv.y, acc0[r]);
      acc0[r] = fmaf(w0[2], hv.z, acc0[r]);
      acc0[r] = fmaf(w0[3], hv.w, acc0[r]);
      acc1[r] = fmaf(w1v[0], hv.x, acc1[r]);
      acc1[r] = fmaf(w1v[1], hv.y, acc1[r]);
      acc1[r] = fmaf(w1v[2], hv.z, acc1[r]);
      acc1[r] = fmaf(w1v[3], hv.w, acc1[r]);
    }
  }
  {
    float bb0 = b2[j0];
    float bb1 = p2 ? b2[j1] : 0.f;
#pragma unroll
    for (int r = 0; r < 16; r++) {
      H2s[r * 304 + j0] = fmaxf(acc0[r] + bb0, 0.f);
      if (p2) H2s[r * 304 + j1] = fmaxf(acc1[r] + bb1, 0.f);
    }
  }
  __syncthreads();

  const int o = tid & 63, wgp = tid >> 6;
  float a3[4];
#pragma unroll
  for (int i = 0; i < 4; i++) a3[i] = 0.f;
  for (int k4 = 0; k4 < 75; k4++) {
    float w3v[4];
#pragma unroll
    for (int kk = 0; kk < 4; kk++) w3v[kk] = w3T[(k4 * 4 + kk) * 64 + o];
#pragma unroll
    for (int i = 0; i < 4; i++) {
      float4 hv = *(const float4*)&H2s[(wgp * 4 + i) * 304 + k4 * 4];
      a3[i] = fmaf(w3v[0], hv.x, a3[i]);
      a3[i] = fmaf(w3v[1], hv.y, a3[i]);
      a3[i] = fmaf(w3v[2], hv.z, a3[i]);
      a3[i] = fmaf(w3v[3], hv.w, a3[i]);
    }
  }
  {
    float b3o = b3[o];
#pragma unroll
    for (int i = 0; i < 4; i++) {
      float v = a3[i] + b3o;
      float ss = v * v;
#pragma unroll
      for (int off = 32; off; off >>= 1) ss += __shfl_xor(ss, off, 64);
      float inv = 1.f / fmaxf(sqrtf(ss), 1e-12f);
      int g = r0 + wgp * 4 + i;
      int node = node_base + (g >> LOGB), b = g & (BN - 1);
      int child = 2 * node + 1 + (o >> 5);
      msg_in_out[((child << LOGB) + b) * 32 + (o & 31)] = v * inv;
    }
  }
}

extern "C" void kernel_launch(void* const* d_in, const int* in_sizes, int n_in,
                              void* d_out, int out_size, void* d_ws, size_t ws_size,
                              hipStream_t stream) {
  const float* x    = (const float*)d_in[0];
  const float* u    = (const float*)d_in[1];
  const float* up1w = (const float*)d_in[2];  const float* up1b = (const float*)d_in[3];
  const float* up2w = (const float*)d_in[4];  const float* up2b = (const float*)d_in[5];
  const float* up3w = (const float*)d_in[6];  const float* up3b = (const float*)d_in[7];
  const float* q1w1 = (const float*)d_in[8];  const float* q1b1 = (const float*)d_in[9];
  const float* q1w2 = (const float*)d_in[10]; const float* q1b2 = (const float*)d_in[11];
  const float* q1w3 = (const float*)d_in[12]; const float* q1b3 = (const float*)d_in[13];
  const float* q2w1 = (const float*)d_in[14]; const float* q2b1 = (const float*)d_in[15];
  const float* q2w2 = (const float*)d_in[16]; const float* q2b2 = (const float*)d_in[17];
  const float* q2w3 = (const float*)d_in[18]; const float* q2b3 = (const float*)d_in[19];
  const float* mbw1 = (const float*)d_in[20]; const float* mbb1 = (const float*)d_in[21];
  const float* mbw2 = (const float*)d_in[22]; const float* mbb2 = (const float*)d_in[23];
  const float* mbw3 = (const float*)d_in[24]; const float* mbb3 = (const float*)d_in[25];
  float* out = (float*)d_out;
  float* ws  = (float*)d_ws;

  float* msg_up = ws;                        // 15*8192*32
  float* msg_in = msg_up + 15 * BN * 32;     // 15*8192*32
  float* t_up1  = msg_in + 15 * BN * 32;     // [33][64]
  float* t_up2  = t_up1 + 33 * 64;           // [128][64]
  float* t_up3  = t_up2 + 128 * 64;          // [64][32]
  float* t_q1w1 = t_up3 + 64 * 32;           // [68][400]
  float* t_q1w2 = t_q1w1 + 68 * 400;         // [400][300]
  float* t_q2w1 = t_q1w2 + 400 * 300;        // [68][400]
  float* t_q2w2 = t_q2w1 + 68 * 400;         // [400][300]
  float* t_mbw1 = t_q2w2 + 400 * 300;        // [64][400]
  float* t_mbw2 = t_mbw1 + 64 * 400;         // [400][300]
  float* t_mbw3 = t_mbw2 + 400 * 300;        // [300][64]

  auto tp = [&](const float* s, float* d, int R, int C, int Cpad) {
    int n = Cpad * R;
    k_transpose_pad<<<dim3((n + 255) / 256), dim3(256), 0, stream>>>(s, d, R, C, Cpad);
  };
  tp(up1w, t_up1, 64, 33, 33);
  tp(up2w, t_up2, 64, 128, 128);
  tp(up3w, t_up3, 32, 64, 64);
  tp(q1w1, t_q1w1, 400, 65, 68);
  tp(q1w2, t_q1w2, 300, 400, 400);
  tp(q2w1, t_q2w1, 400, 65, 68);
  tp(q2w2, t_q2w2, 300, 400, 400);
  tp(mbw1, t_mbw1, 400, 64, 64);
  tp(mbw2, t_mbw2, 300, 400, 400);
  tp(mbw3, t_mbw3, 64, 300, 300);

  // ---- bottom-up: deepest level first ----
  const int up_base[4] = {7, 3, 1, 0};
  const int up_n[4]    = {8, 4, 2, 1};
  const int up_hc[4]   = {0, 1, 1, 1};
  for (int i = 0; i < 4; i++) {
    k_up<<<dim3(up_n[i] * (BN / 32)), dim3(256), 0, stream>>>(
        x, u, t_up1, up1b, t_up2, up2b, t_up3, up3b, msg_up, up_base[i], up_hc[i]);
  }

  // ---- top-down ----
  const int dn_base[4] = {0, 1, 3, 7};
  const int dn_n[4]    = {1, 2, 4, 8};
  const int dn_hp[4]   = {0, 1, 1, 1};
  for (int li = 0; li < 4; li++) {
    int base = dn_base[li], n = dn_n[li], hp = dn_hp[li];
    k_down_q<<<dim3(n * (BN / 32)), dim3(256), 0, stream>>>(
        msg_up, u, msg_in, t_q1w1, q1b1, t_q1w2, q1b2, q1w3, q1b3, out, base, hp, 0);
    k_down_q<<<dim3(n * (BN / 32)), dim3(256), 0, stream>>>(
        msg_up, u, msg_in, t_q2w1, q2b1, t_q2w2, q2b2, q2w3, q2b3, out, base, hp, 1);
    if (li < 3) {
      k_down_mb<<<dim3(n * (BN / 16)), dim3(256), 0, stream>>>(
          msg_up, msg_in, t_mbw1, mbb1, t_mbw2, mbb2, t_mbw3, mbb3, msg_in, base, hp);
    }
  }
}

// Round 2
// 337.216 us; speedup vs baseline: 8.3387x; 8.3387x over previous
//
#include <hip/hip_runtime.h>

#define BN 8192
#define LOGB 13

typedef __attribute__((ext_vector_type(8))) short short8;
typedef __attribute__((ext_vector_type(4))) float f32x4;

__device__ __forceinline__ float tanh_fast(float x) {
  x = fminf(fmaxf(x, -15.f), 15.f);
  float t = __expf(2.f * x);
  return (t - 1.f) / (t + 1.f);
}

__device__ __forceinline__ unsigned short f2bf(float f) {
  unsigned u = __float_as_uint(f);
  unsigned r = (u + 0x7FFFu + ((u >> 16) & 1u)) >> 16;
  return (unsigned short)r;
}

// dst layout [Cpad][R]; dst[c][r] = (c<C) ? src[r][c] : 0   (for up-pass fp32 weights)
__global__ __launch_bounds__(256) void k_transpose_pad(
    const float* __restrict__ src, float* __restrict__ dst, int R, int C, int Cpad) {
  int i = blockIdx.x * 256 + threadIdx.x;
  if (i >= Cpad * R) return;
  int c = i / R, r = i - c * R;
  dst[i] = (c < C) ? src[r * C + c] : 0.f;
}

// Pack W[N][Ksrc] fp32 -> bf16 MFMA B-fragment order:
// dst[((nt*nKs+ks)*64 + lane)*8 + j] = W[nt*16+(lane&15)][kmap(ks*32+(lane>>4)*8+j)]
// kmap skips column `skip` (for q layer-1, u column peeled out), zero-pads OOB.
__global__ __launch_bounds__(256) void k_pack(
    const float* __restrict__ W, unsigned short* __restrict__ dst,
    int Nsrc, int Ksrc, int nNt, int nKs, int skip) {
  int i = blockIdx.x * 256 + threadIdx.x;
  int total = nNt * nKs * 512;
  if (i >= total) return;
  int j = i & 7, l = (i >> 3) & 63, fi = i >> 9;
  int ks = fi % nKs, nt = fi / nKs;
  int n = nt * 16 + (l & 15);
  int k = ks * 32 + ((l >> 4) << 3) + j;
  if (skip >= 0 && k >= skip) k++;
  float v = (n < Nsrc && k < Ksrc) ? W[n * Ksrc + k] : 0.f;
  dst[i] = f2bf(v);
}

// ---------------- bottom-up CriticUp: fp32 VALU, 32 rows/block ----------------
__global__ __launch_bounds__(256, 2) void k_up(
    const float* __restrict__ x, const float* __restrict__ u,
    const float* __restrict__ w1T, const float* __restrict__ b1,   // [33][64]
    const float* __restrict__ w2T, const float* __restrict__ b2,   // [128][64]
    const float* __restrict__ w3T, const float* __restrict__ b3,   // [64][32]
    float* __restrict__ msg_up, int node_base, int has_children) {
  __shared__ float Xs[32][34];
  __shared__ float Hs[32][128];
  __shared__ float H2s[32][64];
  const int tid = threadIdx.x;
  const int r0 = blockIdx.x * 32;

  for (int f = tid; f < 32 * 33; f += 256) {
    int r = f / 33, c = f - r * 33;
    int g = r0 + r;
    int node = node_base + (g >> LOGB), b = g & (BN - 1);
    int rb = (node << LOGB) + b;
    Xs[r][c] = (c < 32) ? x[rb * 32 + c] : u[rb];
  }
  for (int f = tid; f < 32 * 64; f += 256) {
    int r = f >> 6, c = f & 63;
    float v = 0.f;
    if (has_children) {
      int g = r0 + r;
      int node = node_base + (g >> LOGB), b = g & (BN - 1);
      int child = 2 * node + 1 + (c >> 5);
      v = msg_up[((child << LOGB) + b) * 32 + (c & 31)];
    }
    Hs[r][64 + c] = tanh_fast(v);
  }
  __syncthreads();

  const int j = tid & 63, w = tid >> 6;
  float acc[8];
#pragma unroll
  for (int i = 0; i < 8; i++) acc[i] = 0.f;
  for (int k = 0; k < 33; k++) {
    float wv = w1T[k * 64 + j];
#pragma unroll
    for (int i = 0; i < 8; i++) acc[i] = fmaf(wv, Xs[w * 8 + i][k], acc[i]);
  }
  {
    float bj = b1[j];
#pragma unroll
    for (int i = 0; i < 8; i++) {
      float v = acc[i] + bj;
      float ss = v * v;
#pragma unroll
      for (int off = 32; off; off >>= 1) ss += __shfl_xor(ss, off, 64);
      float inv = 1.f / fmaxf(sqrtf(ss), 1e-12f);
      Hs[w * 8 + i][j] = tanh_fast(v * inv);
    }
  }
  __syncthreads();

#pragma unroll
  for (int i = 0; i < 8; i++) acc[i] = 0.f;
  for (int k = 0; k < 128; k++) {
    float wv = w2T[k * 64 + j];
#pragma unroll
    for (int i = 0; i < 8; i++) acc[i] = fmaf(wv, Hs[w * 8 + i][k], acc[i]);
  }
  {
    float b2j = b2[j];
#pragma unroll
    for (int i = 0; i < 8; i++) H2s[w * 8 + i][j] = tanh_fast(acc[i] + b2j);
  }
  __syncthreads();

  const int o = tid & 31, rg = tid >> 5;
  float a3[4];
#pragma unroll
  for (int i = 0; i < 4; i++) a3[i] = 0.f;
  for (int k = 0; k < 64; k++) {
    float wv = w3T[k * 32 + o];
#pragma unroll
    for (int i = 0; i < 4; i++) a3[i] = fmaf(wv, H2s[rg * 4 + i][k], a3[i]);
  }
  {
    float b3o = b3[o];
#pragma unroll
    for (int i = 0; i < 4; i++) {
      float v = a3[i] + b3o;
      float ss = v * v;
#pragma unroll
      for (int off = 16; off; off >>= 1) ss += __shfl_xor(ss, off, 32);
      float inv = 1.f / fmaxf(sqrtf(ss), 1e-12f);
      int g = r0 + rg * 4 + i;
      int node = node_base + (g >> LOGB), b = g & (BN - 1);
      msg_up[((node << LOGB) + b) * 32 + o] = v * inv;
    }
  }
}

// ---------------- top-down Q nets via MFMA: 64 rows/block, q1+q2 via blockIdx.y ----------------
// Layer1: K=64 (u column peeled as rank-1), N=400.  Layer2: K=400(pad416), N=300(pad304), fused dot w3.
__global__ __launch_bounds__(256, 2) void k_q_mfma(
    const float* __restrict__ msg_up, const float* __restrict__ u,
    const float* __restrict__ msg_in,
    const unsigned short* __restrict__ w1fA, const unsigned short* __restrict__ w2fA,
    const float* __restrict__ w1oA, const float* __restrict__ b1A,
    const float* __restrict__ b2A, const float* __restrict__ w3A, const float* __restrict__ b3A,
    const unsigned short* __restrict__ w1fB, const unsigned short* __restrict__ w2fB,
    const float* __restrict__ w1oB, const float* __restrict__ b1B,
    const float* __restrict__ b2B, const float* __restrict__ w3B, const float* __restrict__ b3B,
    float* __restrict__ out, int node_base, int has_parent) {
  __shared__ __align__(16) unsigned short Xs[64 * 72];    // stride 72: conflict-free b128
  __shared__ __align__(16) unsigned short H1s[64 * 424];  // stride 424: conflict-free b128
  __shared__ float u_s[64];
  __shared__ float Red[4][64];
  const int tid = threadIdx.x;
  const int net = blockIdx.y;
  const unsigned short* w1f = net ? w1fB : w1fA;
  const unsigned short* w2f = net ? w2fB : w2fA;
  const float* w1o = net ? w1oB : w1oA;
  const float* b1 = net ? b1B : b1A;
  const float* b2 = net ? b2B : b2A;
  const float* w3 = net ? w3B : w3A;
  const float* b3 = net ? b3B : b3A;
  const int r0 = blockIdx.x * 64;

  for (int f = tid; f < 64 * 64; f += 256) {
    int r = f >> 6, c = f & 63;
    int g = r0 + r;
    int node = node_base + (g >> LOGB), b = g & (BN - 1);
    int rb = (node << LOGB) + b;
    float v = (c < 32) ? msg_up[rb * 32 + c]
                       : (has_parent ? msg_in[rb * 32 + (c - 32)] : 0.f);
    Xs[r * 72 + c] = f2bf(v);
  }
  for (int f = tid; f < 64 * 16; f += 256)
    H1s[(f >> 4) * 424 + 400 + (f & 15)] = 0;   // K-pad cols must be finite zero
  if (tid < 64) {
    int g = r0 + tid;
    int node = node_base + (g >> LOGB), b = g & (BN - 1);
    u_s[tid] = u[(node << LOGB) + b];
  }
  __syncthreads();

  const int w = tid >> 6, l = tid & 63;
  const int lr = l & 15, lh = l >> 4;

  // ---- layer 1: X[64x64] @ W1T -> H1[64x400] ----
  const int nb1 = (w == 0) ? 0 : (1 + 6 * w);
  const int nc1 = (w == 0) ? 7 : 6;
  f32x4 acc1[7][4];
#pragma unroll
  for (int i = 0; i < 7; i++)
#pragma unroll
    for (int m = 0; m < 4; m++) acc1[i][m] = (f32x4)(0.f);
  const short8* w1v = (const short8*)w1f;
#pragma unroll
  for (int ks = 0; ks < 2; ks++) {
    short8 a[4];
#pragma unroll
    for (int m = 0; m < 4; m++)
      a[m] = *(const short8*)&Xs[(m * 16 + lr) * 72 + ks * 32 + lh * 8];
    short8 bf[7];
#pragma unroll
    for (int nt = 0; nt < 7; nt++)
      if (nt < nc1) bf[nt] = w1v[((nb1 + nt) * 2 + ks) * 64 + l];
#pragma unroll
    for (int nt = 0; nt < 7; nt++)
      if (nt < nc1)
#pragma unroll
        for (int m = 0; m < 4; m++)
          acc1[nt][m] = __builtin_amdgcn_mfma_f32_16x16x32_bf16(a[m], bf[nt], acc1[nt][m], 0, 0, 0);
  }
  // rank-1 u column + bias + ReLU -> H1 (bf16)
  float uv[4][4];
#pragma unroll
  for (int m = 0; m < 4; m++)
#pragma unroll
    for (int r = 0; r < 4; r++) uv[m][r] = u_s[m * 16 + lh * 4 + r];
#pragma unroll
  for (int nt = 0; nt < 7; nt++)
    if (nt < nc1) {
      int n = (nb1 + nt) * 16 + lr;
      float wu = w1o[n * 65 + 32];
      float bb = b1[n];
#pragma unroll
      for (int m = 0; m < 4; m++)
#pragma unroll
        for (int r = 0; r < 4; r++) {
          float h = acc1[nt][m][r] + uv[m][r] * wu + bb;
          h = fmaxf(h, 0.f);
          H1s[(m * 16 + lh * 4 + r) * 424 + n] = f2bf(h);
        }
    }
  __syncthreads();

  // ---- layer 2: H1 @ W2T -> (ReLU) -> fused dot w3 ----
  const int nb2 = 5 * w;
  const int nc2 = (w < 3) ? 5 : 4;
  f32x4 acc2[5][4];
#pragma unroll
  for (int i = 0; i < 5; i++)
#pragma unroll
    for (int m = 0; m < 4; m++) acc2[i][m] = (f32x4)(0.f);
  const short8* w2v = (const short8*)w2f;
  for (int ks = 0; ks < 13; ks++) {
    short8 a[4];
#pragma unroll
    for (int m = 0; m < 4; m++)
      a[m] = *(const short8*)&H1s[(m * 16 + lr) * 424 + ks * 32 + lh * 8];
    short8 bf[5];
#pragma unroll
    for (int nt = 0; nt < 5; nt++)
      if (nt < nc2) bf[nt] = w2v[((nb2 + nt) * 13 + ks) * 64 + l];
#pragma unroll
    for (int nt = 0; nt < 5; nt++)
      if (nt < nc2)
#pragma unroll
        for (int m = 0; m < 4; m++)
          acc2[nt][m] = __builtin_amdgcn_mfma_f32_16x16x32_bf16(a[m], bf[nt], acc2[nt][m], 0, 0, 0);
  }
  float part[4][4];
#pragma unroll
  for (int m = 0; m < 4; m++)
#pragma unroll
    for (int r = 0; r < 4; r++) part[m][r] = 0.f;
#pragma unroll
  for (int nt = 0; nt < 5; nt++)
    if (nt < nc2) {
      int n = (nb2 + nt) * 16 + lr;
      float bb = (n < 300) ? b2[n] : 0.f;
      float w3n = (n < 300) ? w3[n] : 0.f;
#pragma unroll
      for (int m = 0; m < 4; m++)
#pragma unroll
        for (int r = 0; r < 4; r++) {
          float h = fmaxf(acc2[nt][m][r] + bb, 0.f);
          part[m][r] = fmaf(h, w3n, part[m][r]);
        }
    }
#pragma unroll
  for (int m = 0; m < 4; m++)
#pragma unroll
    for (int r = 0; r < 4; r++) {
      float p = part[m][r];
      p += __shfl_xor(p, 1, 64);
      p += __shfl_xor(p, 2, 64);
      p += __shfl_xor(p, 4, 64);
      p += __shfl_xor(p, 8, 64);
      if (lr == 0) Red[w][m * 16 + lh * 4 + r] = p;
    }
  __syncthreads();
  if (tid < 64) {
    int g = r0 + tid;
    int node = node_base + (g >> LOGB), b = g & (BN - 1);
    float q = Red[0][tid] + Red[1][tid] + Red[2][tid] + Red[3][tid] + b3[0];
    out[(((node) << LOGB) + b) * 2 + net] = q;
  }
}

// ---------------- top-down message net via MFMA: 32 rows/block ----------------
// Layer1: K=64 (tanh input), N=400. Layer2: K=416, N=304. Layer3: K=320, N=64 + normalize + scatter.
__global__ __launch_bounds__(256, 2) void k_mb_mfma(
    const float* __restrict__ msg_up, const float* __restrict__ msg_in,
    const unsigned short* __restrict__ w1f, const unsigned short* __restrict__ w2f,
    const unsigned short* __restrict__ w3f,
    const float* __restrict__ b1, const float* __restrict__ b2, const float* __restrict__ b3,
    float* __restrict__ msg_in_out, int node_base, int has_parent) {
  __shared__ __align__(16) unsigned short Xs[32 * 72];
  __shared__ __align__(16) unsigned short H1s[32 * 424];
  __shared__ __align__(16) unsigned short H2s[32 * 328];
  __shared__ float RedM[4][32];
  const int tid = threadIdx.x;
  const int r0 = blockIdx.x * 32;

  for (int f = tid; f < 32 * 64; f += 256) {
    int r = f >> 6, c = f & 63;
    int g = r0 + r;
    int node = node_base + (g >> LOGB), b = g & (BN - 1);
    int rb = (node << LOGB) + b;
    float v = (c < 32) ? msg_up[rb * 32 + c]
                       : (has_parent ? msg_in[rb * 32 + (c - 32)] : 0.f);
    Xs[r * 72 + c] = f2bf(tanh_fast(v));
  }
  for (int f = tid; f < 32 * 16; f += 256)
    H1s[(f >> 4) * 424 + 400 + (f & 15)] = 0;
  for (int f = tid; f < 32 * 20; f += 256)
    H2s[(f / 20) * 328 + 300 + (f % 20)] = 0;
  __syncthreads();

  const int w = tid >> 6, l = tid & 63;
  const int lr = l & 15, lh = l >> 4;

  // ---- layer 1 ----
  const int nb1 = (w == 0) ? 0 : (1 + 6 * w);
  const int nc1 = (w == 0) ? 7 : 6;
  f32x4 acc1[7][2];
#pragma unroll
  for (int i = 0; i < 7; i++)
#pragma unroll
    for (int m = 0; m < 2; m++) acc1[i][m] = (f32x4)(0.f);
  const short8* w1v = (const short8*)w1f;
#pragma unroll
  for (int ks = 0; ks < 2; ks++) {
    short8 a[2];
#pragma unroll
    for (int m = 0; m < 2; m++)
      a[m] = *(const short8*)&Xs[(m * 16 + lr) * 72 + ks * 32 + lh * 8];
    short8 bf[7];
#pragma unroll
    for (int nt = 0; nt < 7; nt++)
      if (nt < nc1) bf[nt] = w1v[((nb1 + nt) * 2 + ks) * 64 + l];
#pragma unroll
    for (int nt = 0; nt < 7; nt++)
      if (nt < nc1)
#pragma unroll
        for (int m = 0; m < 2; m++)
          acc1[nt][m] = __builtin_amdgcn_mfma_f32_16x16x32_bf16(a[m], bf[nt], acc1[nt][m], 0, 0, 0);
  }
#pragma unroll
  for (int nt = 0; nt < 7; nt++)
    if (nt < nc1) {
      int n = (nb1 + nt) * 16 + lr;
      float bb = b1[n];
#pragma unroll
      for (int m = 0; m < 2; m++)
#pragma unroll
        for (int r = 0; r < 4; r++) {
          float h = fmaxf(acc1[nt][m][r] + bb, 0.f);
          H1s[(m * 16 + lh * 4 + r) * 424 + n] = f2bf(h);
        }
    }
  __syncthreads();

  // ---- layer 2 ----
  const int nb2 = 5 * w;
  const int nc2 = (w < 3) ? 5 : 4;
  f32x4 acc2[5][2];
#pragma unroll
  for (int i = 0; i < 5; i++)
#pragma unroll
    for (int m = 0; m < 2; m++) acc2[i][m] = (f32x4)(0.f);
  const short8* w2v = (const short8*)w2f;
  for (int ks = 0; ks < 13; ks++) {
    short8 a[2];
#pragma unroll
    for (int m = 0; m < 2; m++)
      a[m] = *(const short8*)&H1s[(m * 16 + lr) * 424 + ks * 32 + lh * 8];
    short8 bf[5];
#pragma unroll
    for (int nt = 0; nt < 5; nt++)
      if (nt < nc2) bf[nt] = w2v[((nb2 + nt) * 13 + ks) * 64 + l];
#pragma unroll
    for (int nt = 0; nt < 5; nt++)
      if (nt < nc2)
#pragma unroll
        for (int m = 0; m < 2; m++)
          acc2[nt][m] = __builtin_amdgcn_mfma_f32_16x16x32_bf16(a[m], bf[nt], acc2[nt][m], 0, 0, 0);
  }
#pragma unroll
  for (int nt = 0; nt < 5; nt++)
    if (nt < nc2) {
      int n = (nb2 + nt) * 16 + lr;
      float bb = (n < 300) ? b2[n] : 0.f;
#pragma unroll
      for (int m = 0; m < 2; m++)
#pragma unroll
        for (int r = 0; r < 4; r++) {
          float h = (n < 300) ? fmaxf(acc2[nt][m][r] + bb, 0.f) : 0.f;
          H2s[(m * 16 + lh * 4 + r) * 328 + n] = f2bf(h);
        }
    }
  __syncthreads();

  // ---- layer 3: K=320 -> N=64, one N-tile per wave; normalize + scatter to children ----
  f32x4 acc3[2];
#pragma unroll
  for (int m = 0; m < 2; m++) acc3[m] = (f32x4)(0.f);
  const short8* w3v = (const short8*)w3f;
  for (int ks = 0; ks < 10; ks++) {
    short8 a[2];
#pragma unroll
    for (int m = 0; m < 2; m++)
      a[m] = *(const short8*)&H2s[(m * 16 + lr) * 328 + ks * 32 + lh * 8];
    short8 bfr = w3v[(w * 10 + ks) * 64 + l];
#pragma unroll
    for (int m = 0; m < 2; m++)
      acc3[m] = __builtin_amdgcn_mfma_f32_16x16x32_bf16(a[m], bfr, acc3[m], 0, 0, 0);
  }
  const int n3 = w * 16 + lr;
  float vout[2][4];
  {
    float bb = b3[n3];
#pragma unroll
    for (int m = 0; m < 2; m++)
#pragma unroll
      for (int r = 0; r < 4; r++) {
        float v = acc3[m][r] + bb;
        vout[m][r] = v;
        float s = v * v;
        s += __shfl_xor(s, 1, 64);
        s += __shfl_xor(s, 2, 64);
        s += __shfl_xor(s, 4, 64);
        s += __shfl_xor(s, 8, 64);
        if (lr == 0) RedM[w][m * 16 + lh * 4 + r] = s;
      }
  }
  __syncthreads();
#pragma unroll
  for (int m = 0; m < 2; m++)
#pragma unroll
    for (int r = 0; r < 4; r++) {
      int row = m * 16 + lh * 4 + r;
      float ss = RedM[0][row] + RedM[1][row] + RedM[2][row] + RedM[3][row];
      float inv = 1.f / fmaxf(sqrtf(ss), 1e-12f);
      int g = r0 + row;
      int node = node_base + (g >> LOGB), b = g & (BN - 1);
      int child = 2 * node + 1 + (n3 >> 5);
      msg_in_out[((child << LOGB) + b) * 32 + (n3 & 31)] = vout[m][r] * inv;
    }
}

extern "C" void kernel_launch(void* const* d_in, const int* in_sizes, int n_in,
                              void* d_out, int out_size, void* d_ws, size_t ws_size,
                              hipStream_t stream) {
  const float* x    = (const float*)d_in[0];
  const float* u    = (const float*)d_in[1];
  const float* up1w = (const float*)d_in[2];  const float* up1b = (const float*)d_in[3];
  const float* up2w = (const float*)d_in[4];  const float* up2b = (const float*)d_in[5];
  const float* up3w = (const float*)d_in[6];  const float* up3b = (const float*)d_in[7];
  const float* q1w1 = (const float*)d_in[8];  const float* q1b1 = (const float*)d_in[9];
  const float* q1w2 = (const float*)d_in[10]; const float* q1b2 = (const float*)d_in[11];
  const float* q1w3 = (const float*)d_in[12]; const float* q1b3 = (const float*)d_in[13];
  const float* q2w1 = (const float*)d_in[14]; const float* q2b1 = (const float*)d_in[15];
  const float* q2w2 = (const float*)d_in[16]; const float* q2b2 = (const float*)d_in[17];
  const float* q2w3 = (const float*)d_in[18]; const float* q2b3 = (const float*)d_in[19];
  const float* mbw1 = (const float*)d_in[20]; const float* mbb1 = (const float*)d_in[21];
  const float* mbw2 = (const float*)d_in[22]; const float* mbb2 = (const float*)d_in[23];
  const float* mbw3 = (const float*)d_in[24]; const float* mbb3 = (const float*)d_in[25];
  float* out = (float*)d_out;
  float* ws  = (float*)d_ws;

  float* msg_up = ws;                        // 15*8192*32
  float* msg_in = msg_up + 15 * BN * 32;     // 15*8192*32
  float* t_up1  = msg_in + 15 * BN * 32;     // [33][64]
  float* t_up2  = t_up1 + 33 * 64;           // [128][64]
  float* t_up3  = t_up2 + 128 * 64;          // [64][32]
  unsigned short* frag = (unsigned short*)(t_up3 + 64 * 32);
  unsigned short* q1w1f = frag;              // 25*2*512  = 25600
  unsigned short* q1w2f = q1w1f + 25600;     // 19*13*512 = 126464
  unsigned short* q2w1f = q1w2f + 126464;
  unsigned short* q2w2f = q2w1f + 25600;
  unsigned short* mbw1f = q2w2f + 126464;    // 25*2*512
  unsigned short* mbw2f = mbw1f + 25600;     // 19*13*512
  unsigned short* mbw3f = mbw2f + 126464;    // 4*10*512 = 20480

  auto tp = [&](const float* s, float* d, int R, int C, int Cpad) {
    int n = Cpad * R;
    k_transpose_pad<<<dim3((n + 255) / 256), dim3(256), 0, stream>>>(s, d, R, C, Cpad);
  };
  tp(up1w, t_up1, 64, 33, 33);
  tp(up2w, t_up2, 64, 128, 128);
  tp(up3w, t_up3, 32, 64, 64);

  auto pk = [&](const float* s, unsigned short* d, int N, int K, int nNt, int nKs, int skip) {
    int n = nNt * nKs * 512;
    k_pack<<<dim3((n + 255) / 256), dim3(256), 0, stream>>>(s, d, N, K, nNt, nKs, skip);
  };
  pk(q1w1, q1w1f, 400, 65, 25, 2, 32);
  pk(q1w2, q1w2f, 300, 400, 19, 13, -1);
  pk(q2w1, q2w1f, 400, 65, 25, 2, 32);
  pk(q2w2, q2w2f, 300, 400, 19, 13, -1);
  pk(mbw1, mbw1f, 400, 64, 25, 2, -1);
  pk(mbw2, mbw2f, 300, 400, 19, 13, -1);
  pk(mbw3, mbw3f, 64, 300, 4, 10, -1);

  // ---- bottom-up ----
  const int up_base[4] = {7, 3, 1, 0};
  const int up_n[4]    = {8, 4, 2, 1};
  const int up_hc[4]   = {0, 1, 1, 1};
  for (int i = 0; i < 4; i++) {
    k_up<<<dim3(up_n[i] * (BN / 32)), dim3(256), 0, stream>>>(
        x, u, t_up1, up1b, t_up2, up2b, t_up3, up3b, msg_up, up_base[i], up_hc[i]);
  }

  // ---- top-down ----
  const int dn_base[4] = {0, 1, 3, 7};
  const int dn_n[4]    = {1, 2, 4, 8};
  const int dn_hp[4]   = {0, 1, 1, 1};
  for (int li = 0; li < 4; li++) {
    int base = dn_base[li], n = dn_n[li], hp = dn_hp[li];
    k_q_mfma<<<dim3(n * (BN / 64), 2), dim3(256), 0, stream>>>(
        msg_up, u, msg_in,
        q1w1f, q1w2f, q1w1, q1b1, q1b2, q1w3, q1b3,
        q2w1f, q2w2f, q2w1, q2b1, q2b2, q2w3, q2b3,
        out, base, hp);
    if (li < 3) {
      k_mb_mfma<<<dim3(n * (BN / 32)), dim3(256), 0, stream>>>(
          msg_up, msg_in, mbw1f, mbw2f, mbw3f, mbb1, mbb2, mbb3, msg_in, base, hp);
    }
  }
}

// Round 3
// 281.604 us; speedup vs baseline: 9.9854x; 1.1975x over previous
//
#include <hip/hip_runtime.h>

#define BN 8192
#define LOGB 13

typedef __attribute__((ext_vector_type(8))) short short8;
typedef __attribute__((ext_vector_type(4))) float f32x4;

__device__ __forceinline__ float tanh_fast(float x) {
  x = fminf(fmaxf(x, -15.f), 15.f);
  float t = __expf(2.f * x);
  return (t - 1.f) / (t + 1.f);
}

__device__ __forceinline__ unsigned short f2bf(float f) {
  unsigned u = __float_as_uint(f);
  unsigned r = (u + 0x7FFFu + ((u >> 16) & 1u)) >> 16;
  return (unsigned short)r;
}

// ---- prep: 3 transposes in one kernel ----
__global__ __launch_bounds__(256) void k_prep_tr(
    const float* __restrict__ s0, const float* __restrict__ s1, const float* __restrict__ s2,
    float* __restrict__ d0, float* __restrict__ d1, float* __restrict__ d2) {
  int i = blockIdx.x * 256 + threadIdx.x;
  // seg0: up1w 64x33 -> [33][64] (2112); seg1: up2w 64x128 (8192); seg2: up3w 32x64 (2048)
  if (i < 2112) {
    int c = i / 64, r = i - c * 64;
    d0[i] = s0[r * 33 + c];
  } else if (i < 2112 + 8192) {
    int j = i - 2112;
    int c = j / 64, r = j - c * 64;
    d1[j] = s1[r * 128 + c];
  } else if (i < 2112 + 8192 + 2048) {
    int j = i - 2112 - 8192;
    int c = j / 32, r = j - c * 32;
    d2[j] = s2[r * 64 + c];
  }
}

// ---- prep: 7 weight packs in one kernel ----
// pack: dst[((nt*nKs+ks)*64+l)*8+j] = W[nt*16+(l&15)][kmap(ks*32+(l>>4)*8+j)]
__device__ __forceinline__ void pack_one(
    const float* __restrict__ W, unsigned short* __restrict__ dst,
    int i, int Nsrc, int Ksrc, int nKs, int skip) {
  int j = i & 7, l = (i >> 3) & 63, fi = i >> 9;
  int ks = fi % nKs, nt = fi / nKs;
  int n = nt * 16 + (l & 15);
  int k = ks * 32 + ((l >> 4) << 3) + j;
  if (skip >= 0 && k >= skip) k++;
  float v = (n < Nsrc && k < Ksrc) ? W[n * Ksrc + k] : 0.f;
  dst[i] = f2bf(v);
}

__global__ __launch_bounds__(256) void k_prep_pack(
    const float* __restrict__ s0, unsigned short* __restrict__ d0,   // q1w1 400x65  25600
    const float* __restrict__ s1, unsigned short* __restrict__ d1,   // q1w2 300x400 126464
    const float* __restrict__ s2, unsigned short* __restrict__ d2,   // q2w1
    const float* __restrict__ s3, unsigned short* __restrict__ d3,   // q2w2
    const float* __restrict__ s4, unsigned short* __restrict__ d4,   // mbw1 400x64  25600
    const float* __restrict__ s5, unsigned short* __restrict__ d5,   // mbw2 300x400 126464
    const float* __restrict__ s6, unsigned short* __restrict__ d6) { // mbw3 64x300  20480
  int i = blockIdx.x * 256 + threadIdx.x;
  if (i < 25600) { pack_one(s0, d0, i, 400, 65, 2, 32); return; }
  i -= 25600;
  if (i < 126464) { pack_one(s1, d1, i, 300, 400, 13, -1); return; }
  i -= 126464;
  if (i < 25600) { pack_one(s2, d2, i, 400, 65, 2, 32); return; }
  i -= 25600;
  if (i < 126464) { pack_one(s3, d3, i, 300, 400, 13, -1); return; }
  i -= 126464;
  if (i < 25600) { pack_one(s4, d4, i, 400, 64, 2, -1); return; }
  i -= 25600;
  if (i < 126464) { pack_one(s5, d5, i, 300, 400, 13, -1); return; }
  i -= 126464;
  if (i < 20480) { pack_one(s6, d6, i, 64, 300, 10, -1); return; }
}

// ---------------- bottom-up CriticUp: fp32 VALU, 32 rows/block ----------------
__global__ __launch_bounds__(256, 2) void k_up(
    const float* __restrict__ x, const float* __restrict__ u,
    const float* __restrict__ w1T, const float* __restrict__ b1,   // [33][64]
    const float* __restrict__ w2T, const float* __restrict__ b2,   // [128][64]
    const float* __restrict__ w3T, const float* __restrict__ b3,   // [64][32]
    float* __restrict__ msg_up, int node_base, int has_children) {
  __shared__ float Xs[32][34];
  __shared__ float Hs[32][128];
  __shared__ float H2s[32][64];
  const int tid = threadIdx.x;
  const int r0 = blockIdx.x * 32;

  for (int f = tid; f < 32 * 33; f += 256) {
    int r = f / 33, c = f - r * 33;
    int g = r0 + r;
    int node = node_base + (g >> LOGB), b = g & (BN - 1);
    int rb = (node << LOGB) + b;
    Xs[r][c] = (c < 32) ? x[rb * 32 + c] : u[rb];
  }
  for (int f = tid; f < 32 * 64; f += 256) {
    int r = f >> 6, c = f & 63;
    float v = 0.f;
    if (has_children) {
      int g = r0 + r;
      int node = node_base + (g >> LOGB), b = g & (BN - 1);
      int child = 2 * node + 1 + (c >> 5);
      v = msg_up[((child << LOGB) + b) * 32 + (c & 31)];
    }
    Hs[r][64 + c] = tanh_fast(v);
  }
  __syncthreads();

  const int j = tid & 63, w = tid >> 6;
  float acc[8];
#pragma unroll
  for (int i = 0; i < 8; i++) acc[i] = 0.f;
  for (int k = 0; k < 33; k++) {
    float wv = w1T[k * 64 + j];
#pragma unroll
    for (int i = 0; i < 8; i++) acc[i] = fmaf(wv, Xs[w * 8 + i][k], acc[i]);
  }
  {
    float bj = b1[j];
#pragma unroll
    for (int i = 0; i < 8; i++) {
      float v = acc[i] + bj;
      float ss = v * v;
#pragma unroll
      for (int off = 32; off; off >>= 1) ss += __shfl_xor(ss, off, 64);
      float inv = 1.f / fmaxf(sqrtf(ss), 1e-12f);
      Hs[w * 8 + i][j] = tanh_fast(v * inv);
    }
  }
  __syncthreads();

#pragma unroll
  for (int i = 0; i < 8; i++) acc[i] = 0.f;
  for (int k = 0; k < 128; k++) {
    float wv = w2T[k * 64 + j];
#pragma unroll
    for (int i = 0; i < 8; i++) acc[i] = fmaf(wv, Hs[w * 8 + i][k], acc[i]);
  }
  {
    float b2j = b2[j];
#pragma unroll
    for (int i = 0; i < 8; i++) H2s[w * 8 + i][j] = tanh_fast(acc[i] + b2j);
  }
  __syncthreads();

  const int o = tid & 31, rg = tid >> 5;
  float a3[4];
#pragma unroll
  for (int i = 0; i < 4; i++) a3[i] = 0.f;
  for (int k = 0; k < 64; k++) {
    float wv = w3T[k * 32 + o];
#pragma unroll
    for (int i = 0; i < 4; i++) a3[i] = fmaf(wv, H2s[rg * 4 + i][k], a3[i]);
  }
  {
    float b3o = b3[o];
#pragma unroll
    for (int i = 0; i < 4; i++) {
      float v = a3[i] + b3o;
      float ss = v * v;
#pragma unroll
      for (int off = 16; off; off >>= 1) ss += __shfl_xor(ss, off, 32);
      float inv = 1.f / fmaxf(sqrtf(ss), 1e-12f);
      int g = r0 + rg * 4 + i;
      int node = node_base + (g >> LOGB), b = g & (BN - 1);
      msg_up[((node << LOGB) + b) * 32 + o] = v * inv;
    }
  }
}

// ---------------- Q nets via MFMA: 512 threads, 64 rows/block, ALL 15 nodes, q1/q2 via blockIdx.y ----
__global__ __launch_bounds__(512, 4) void k_q_mfma(
    const float* __restrict__ msg_up, const float* __restrict__ u,
    const float* __restrict__ msg_in,
    const unsigned short* __restrict__ w1fA, const unsigned short* __restrict__ w2fA,
    const float* __restrict__ w1oA, const float* __restrict__ b1A,
    const float* __restrict__ b2A, const float* __restrict__ w3A, const float* __restrict__ b3A,
    const unsigned short* __restrict__ w1fB, const unsigned short* __restrict__ w2fB,
    const float* __restrict__ w1oB, const float* __restrict__ b1B,
    const float* __restrict__ b2B, const float* __restrict__ w3B, const float* __restrict__ b3B,
    float* __restrict__ out) {
  // Xs (64x72 bf16 = 9216B) overlaid with Red (8x64 f32 = 2048B): disjoint lifetimes.
  __shared__ __align__(16) unsigned char sraw[64 * 72 * 2];
  __shared__ __align__(16) unsigned short H1s[64 * 424];   // 54272B
  __shared__ float u_s[64];
  unsigned short* Xs = (unsigned short*)sraw;
  float* Red = (float*)sraw;

  const int tid = threadIdx.x;
  const int net = blockIdx.y;
  const unsigned short* w1f = net ? w1fB : w1fA;
  const unsigned short* w2f = net ? w2fB : w2fA;
  const float* w1o = net ? w1oB : w1oA;
  const float* b1 = net ? b1B : b1A;
  const float* b2 = net ? b2B : b2A;
  const float* w3 = net ? w3B : w3A;
  const float* b3 = net ? b3B : b3A;
  const int r0 = blockIdx.x * 64;            // global row over 15*8192
  const int node = r0 >> LOGB;
  const int has_parent = (node > 0);

  for (int f = tid; f < 64 * 64; f += 512) {
    int r = f >> 6, c = f & 63;
    int row = r0 + r;
    float v = (c < 32) ? msg_up[row * 32 + c]
                       : (has_parent ? msg_in[row * 32 + (c - 32)] : 0.f);
    Xs[r * 72 + c] = f2bf(v);
  }
  for (int f = tid; f < 64 * 16; f += 512)
    H1s[(f >> 4) * 424 + 400 + (f & 15)] = 0;   // K-pad cols 400..415 = 0
  if (tid < 64) u_s[tid] = u[r0 + tid];
  __syncthreads();

  const int w = tid >> 6, l = tid & 63;
  const int lr = l & 15, lh = l >> 4;

  // ---- layer 1: X[64x64] @ W1T -> H1[64x400]; 25 n-tiles split (4,3,3,3,3,3,3,3) ----
  const int nb1 = (w == 0) ? 0 : (3 * w + 1);
  const int nc1 = (w == 0) ? 4 : 3;
  f32x4 acc1[4][4];
#pragma unroll
  for (int i = 0; i < 4; i++)
#pragma unroll
    for (int m = 0; m < 4; m++) acc1[i][m] = (f32x4)(0.f);
  const short8* w1v = (const short8*)w1f;
#pragma unroll
  for (int ks = 0; ks < 2; ks++) {
    short8 a[4];
#pragma unroll
    for (int m = 0; m < 4; m++)
      a[m] = *(const short8*)&Xs[(m * 16 + lr) * 72 + ks * 32 + lh * 8];
    short8 bf[4];
#pragma unroll
    for (int nt = 0; nt < 4; nt++)
      if (nt < nc1) bf[nt] = w1v[((nb1 + nt) * 2 + ks) * 64 + l];
#pragma unroll
    for (int nt = 0; nt < 4; nt++)
      if (nt < nc1)
#pragma unroll
        for (int m = 0; m < 4; m++)
          acc1[nt][m] = __builtin_amdgcn_mfma_f32_16x16x32_bf16(a[m], bf[nt], acc1[nt][m], 0, 0, 0);
  }
  // rank-1 u column + bias + ReLU -> H1 (bf16)
  float uv[4][4];
#pragma unroll
  for (int m = 0; m < 4; m++)
#pragma unroll
    for (int r = 0; r < 4; r++) uv[m][r] = u_s[m * 16 + lh * 4 + r];
#pragma unroll
  for (int nt = 0; nt < 4; nt++)
    if (nt < nc1) {
      int n = (nb1 + nt) * 16 + lr;
      float wu = w1o[n * 65 + 32];
      float bb = b1[n];
#pragma unroll
      for (int m = 0; m < 4; m++)
#pragma unroll
        for (int r = 0; r < 4; r++) {
          float h = acc1[nt][m][r] + uv[m][r] * wu + bb;
          h = fmaxf(h, 0.f);
          H1s[(m * 16 + lh * 4 + r) * 424 + n] = f2bf(h);
        }
    }
  __syncthreads();

  // ---- layer 2: H1 @ W2T; 19 n-tiles split (3,3,3,2,2,2,2,2); fused dot w3 ----
  const int nb2 = (w < 3) ? 3 * w : (9 + 2 * (w - 3));
  const int nc2 = (w < 3) ? 3 : 2;
  f32x4 acc2[3][4];
#pragma unroll
  for (int i = 0; i < 3; i++)
#pragma unroll
    for (int m = 0; m < 4; m++) acc2[i][m] = (f32x4)(0.f);
  const short8* w2v = (const short8*)w2f;
#pragma unroll 2
  for (int ks = 0; ks < 13; ks++) {
    short8 a[4];
#pragma unroll
    for (int m = 0; m < 4; m++)
      a[m] = *(const short8*)&H1s[(m * 16 + lr) * 424 + ks * 32 + lh * 8];
    short8 bf[3];
#pragma unroll
    for (int nt = 0; nt < 3; nt++)
      if (nt < nc2) bf[nt] = w2v[((nb2 + nt) * 13 + ks) * 64 + l];
#pragma unroll
    for (int nt = 0; nt < 3; nt++)
      if (nt < nc2)
#pragma unroll
        for (int m = 0; m < 4; m++)
          acc2[nt][m] = __builtin_amdgcn_mfma_f32_16x16x32_bf16(a[m], bf[nt], acc2[nt][m], 0, 0, 0);
  }
  float part[4][4];
#pragma unroll
  for (int m = 0; m < 4; m++)
#pragma unroll
    for (int r = 0; r < 4; r++) part[m][r] = 0.f;
#pragma unroll
  for (int nt = 0; nt < 3; nt++)
    if (nt < nc2) {
      int n = (nb2 + nt) * 16 + lr;
      float bb = (n < 300) ? b2[n] : 0.f;
      float w3n = (n < 300) ? w3[n] : 0.f;
#pragma unroll
      for (int m = 0; m < 4; m++)
#pragma unroll
        for (int r = 0; r < 4; r++) {
          float h = fmaxf(acc2[nt][m][r] + bb, 0.f);
          part[m][r] = fmaf(h, w3n, part[m][r]);
        }
    }
#pragma unroll
  for (int m = 0; m < 4; m++)
#pragma unroll
    for (int r = 0; r < 4; r++) {
      float p = part[m][r];
      p += __shfl_xor(p, 1, 64);
      p += __shfl_xor(p, 2, 64);
      p += __shfl_xor(p, 4, 64);
      p += __shfl_xor(p, 8, 64);
      if (lr == 0) Red[w * 64 + m * 16 + lh * 4 + r] = p;   // overlay: Xs dead by now
    }
  __syncthreads();
  if (tid < 64) {
    float q = b3[0];
#pragma unroll
    for (int i = 0; i < 8; i++) q += Red[i * 64 + tid];
    out[(r0 + tid) * 2 + net] = q;
  }
}

// ---------------- message net via MFMA: 512 threads, 32 rows/block ----------------
__global__ __launch_bounds__(512, 4) void k_mb_mfma(
    const float* __restrict__ msg_up, const float* __restrict__ msg_in,
    const unsigned short* __restrict__ w1f, const unsigned short* __restrict__ w2f,
    const unsigned short* __restrict__ w3f,
    const float* __restrict__ b1, const float* __restrict__ b2, const float* __restrict__ b3,
    float* __restrict__ msg_in_out, int node_base, int has_parent) {
  __shared__ __align__(16) unsigned short Xs[32 * 72];     // 4608B
  __shared__ __align__(16) unsigned short H1s[32 * 424];   // 27136B
  __shared__ __align__(16) unsigned short H2s[32 * 328];   // 20992B
  __shared__ float RedM[4][32];
  const int tid = threadIdx.x;
  const int r0 = blockIdx.x * 32;

  for (int f = tid; f < 32 * 64; f += 512) {
    int r = f >> 6, c = f & 63;
    int g = r0 + r;
    int node = node_base + (g >> LOGB), b = g & (BN - 1);
    int rb = (node << LOGB) + b;
    float v = (c < 32) ? msg_up[rb * 32 + c]
                       : (has_parent ? msg_in[rb * 32 + (c - 32)] : 0.f);
    Xs[r * 72 + c] = f2bf(tanh_fast(v));
  }
  for (int f = tid; f < 32 * 16; f += 512)
    H1s[(f >> 4) * 424 + 400 + (f & 15)] = 0;
  for (int f = tid; f < 32 * 20; f += 512)
    H2s[(f / 20) * 328 + 300 + (f % 20)] = 0;
  __syncthreads();

  const int w = tid >> 6, l = tid & 63;
  const int lr = l & 15, lh = l >> 4;

  // ---- layer 1: 25 tiles split (4,3x7) ----
  const int nb1 = (w == 0) ? 0 : (3 * w + 1);
  const int nc1 = (w == 0) ? 4 : 3;
  f32x4 acc1[4][2];
#pragma unroll
  for (int i = 0; i < 4; i++)
#pragma unroll
    for (int m = 0; m < 2; m++) acc1[i][m] = (f32x4)(0.f);
  const short8* w1v = (const short8*)w1f;
#pragma unroll
  for (int ks = 0; ks < 2; ks++) {
    short8 a[2];
#pragma unroll
    for (int m = 0; m < 2; m++)
      a[m] = *(const short8*)&Xs[(m * 16 + lr) * 72 + ks * 32 + lh * 8];
    short8 bf[4];
#pragma unroll
    for (int nt = 0; nt < 4; nt++)
      if (nt < nc1) bf[nt] = w1v[((nb1 + nt) * 2 + ks) * 64 + l];
#pragma unroll
    for (int nt = 0; nt < 4; nt++)
      if (nt < nc1)
#pragma unroll
        for (int m = 0; m < 2; m++)
          acc1[nt][m] = __builtin_amdgcn_mfma_f32_16x16x32_bf16(a[m], bf[nt], acc1[nt][m], 0, 0, 0);
  }
#pragma unroll
  for (int nt = 0; nt < 4; nt++)
    if (nt < nc1) {
      int n = (nb1 + nt) * 16 + lr;
      float bb = b1[n];
#pragma unroll
      for (int m = 0; m < 2; m++)
#pragma unroll
        for (int r = 0; r < 4; r++) {
          float h = fmaxf(acc1[nt][m][r] + bb, 0.f);
          H1s[(m * 16 + lh * 4 + r) * 424 + n] = f2bf(h);
        }
    }
  __syncthreads();

  // ---- layer 2: 19 tiles split (3,3,3,2x5) ----
  const int nb2 = (w < 3) ? 3 * w : (9 + 2 * (w - 3));
  const int nc2 = (w < 3) ? 3 : 2;
  f32x4 acc2[3][2];
#pragma unroll
  for (int i = 0; i < 3; i++)
#pragma unroll
    for (int m = 0; m < 2; m++) acc2[i][m] = (f32x4)(0.f);
  const short8* w2v = (const short8*)w2f;
#pragma unroll 2
  for (int ks = 0; ks < 13; ks++) {
    short8 a[2];
#pragma unroll
    for (int m = 0; m < 2; m++)
      a[m] = *(const short8*)&H1s[(m * 16 + lr) * 424 + ks * 32 + lh * 8];
    short8 bf[3];
#pragma unroll
    for (int nt = 0; nt < 3; nt++)
      if (nt < nc2) bf[nt] = w2v[((nb2 + nt) * 13 + ks) * 64 + l];
#pragma unroll
    for (int nt = 0; nt < 3; nt++)
      if (nt < nc2)
#pragma unroll
        for (int m = 0; m < 2; m++)
          acc2[nt][m] = __builtin_amdgcn_mfma_f32_16x16x32_bf16(a[m], bf[nt], acc2[nt][m], 0, 0, 0);
  }
#pragma unroll
  for (int nt = 0; nt < 3; nt++)
    if (nt < nc2) {
      int n = (nb2 + nt) * 16 + lr;
      float bb = (n < 300) ? b2[n] : 0.f;
#pragma unroll
      for (int m = 0; m < 2; m++)
#pragma unroll
        for (int r = 0; r < 4; r++) {
          float h = (n < 300) ? fmaxf(acc2[nt][m][r] + bb, 0.f) : 0.f;
          H2s[(m * 16 + lh * 4 + r) * 328 + n] = f2bf(h);
        }
    }
  __syncthreads();

  // ---- layer 3: K=320 -> N=64; waves 0..3 each own one 16-wide n-tile ----
  if (w < 4) {
    f32x4 acc3[2];
#pragma unroll
    for (int m = 0; m < 2; m++) acc3[m] = (f32x4)(0.f);
    const short8* w3v = (const short8*)w3f;
#pragma unroll 2
    for (int ks = 0; ks < 10; ks++) {
      short8 a[2];
#pragma unroll
      for (int m = 0; m < 2; m++)
        a[m] = *(const short8*)&H2s[(m * 16 + lr) * 328 + ks * 32 + lh * 8];
      short8 bfr = w3v[(w * 10 + ks) * 64 + l];
#pragma unroll
      for (int m = 0; m < 2; m++)
        acc3[m] = __builtin_amdgcn_mfma_f32_16x16x32_bf16(a[m], bfr, acc3[m], 0, 0, 0);
    }
    const int n3 = w * 16 + lr;
    float vout[2][4];
    float bb = b3[n3];
#pragma unroll
    for (int m = 0; m < 2; m++)
#pragma unroll
      for (int r = 0; r < 4; r++) {
        float v = acc3[m][r] + bb;
        vout[m][r] = v;
        float s = v * v;
        s += __shfl_xor(s, 1, 64);
        s += __shfl_xor(s, 2, 64);
        s += __shfl_xor(s, 4, 64);
        s += __shfl_xor(s, 8, 64);
        if (lr == 0) RedM[w][m * 16 + lh * 4 + r] = s;
      }
    __syncthreads();
#pragma unroll
    for (int m = 0; m < 2; m++)
#pragma unroll
      for (int r = 0; r < 4; r++) {
        int row = m * 16 + lh * 4 + r;
        float ss = RedM[0][row] + RedM[1][row] + RedM[2][row] + RedM[3][row];
        float inv = 1.f / fmaxf(sqrtf(ss), 1e-12f);
        int g = r0 + row;
        int node = node_base + (g >> LOGB), b = g & (BN - 1);
        int child = 2 * node + 1 + (n3 >> 5);
        msg_in_out[((child << LOGB) + b) * 32 + (n3 & 31)] = vout[m][r] * inv;
      }
  } else {
    __syncthreads();
  }
}

extern "C" void kernel_launch(void* const* d_in, const int* in_sizes, int n_in,
                              void* d_out, int out_size, void* d_ws, size_t ws_size,
                              hipStream_t stream) {
  const float* x    = (const float*)d_in[0];
  const float* u    = (const float*)d_in[1];
  const float* up1w = (const float*)d_in[2];  const float* up1b = (const float*)d_in[3];
  const float* up2w = (const float*)d_in[4];  const float* up2b = (const float*)d_in[5];
  const float* up3w = (const float*)d_in[6];  const float* up3b = (const float*)d_in[7];
  const float* q1w1 = (const float*)d_in[8];  const float* q1b1 = (const float*)d_in[9];
  const float* q1w2 = (const float*)d_in[10]; const float* q1b2 = (const float*)d_in[11];
  const float* q1w3 = (const float*)d_in[12]; const float* q1b3 = (const float*)d_in[13];
  const float* q2w1 = (const float*)d_in[14]; const float* q2b1 = (const float*)d_in[15];
  const float* q2w2 = (const float*)d_in[16]; const float* q2b2 = (const float*)d_in[17];
  const float* q2w3 = (const float*)d_in[18]; const float* q2b3 = (const float*)d_in[19];
  const float* mbw1 = (const float*)d_in[20]; const float* mbb1 = (const float*)d_in[21];
  const float* mbw2 = (const float*)d_in[22]; const float* mbb2 = (const float*)d_in[23];
  const float* mbw3 = (const float*)d_in[24]; const float* mbb3 = (const float*)d_in[25];
  float* out = (float*)d_out;
  float* ws  = (float*)d_ws;

  float* msg_up = ws;                        // 15*8192*32
  float* msg_in = msg_up + 15 * BN * 32;     // 15*8192*32
  float* t_up1  = msg_in + 15 * BN * 32;     // [33][64]
  float* t_up2  = t_up1 + 33 * 64;           // [128][64]
  float* t_up3  = t_up2 + 128 * 64;          // [64][32]
  unsigned short* frag = (unsigned short*)(t_up3 + 64 * 32);
  unsigned short* q1w1f = frag;              // 25*2*512  = 25600
  unsigned short* q1w2f = q1w1f + 25600;     // 19*13*512 = 126464
  unsigned short* q2w1f = q1w2f + 126464;
  unsigned short* q2w2f = q2w1f + 25600;
  unsigned short* mbw1f = q2w2f + 126464;    // 25*2*512
  unsigned short* mbw2f = mbw1f + 25600;     // 19*13*512
  unsigned short* mbw3f = mbw2f + 126464;    // 4*10*512 = 20480

  // ---- prep: 2 launches ----
  k_prep_tr<<<dim3((12352 + 255) / 256), dim3(256), 0, stream>>>(
      up1w, up2w, up3w, t_up1, t_up2, t_up3);
  k_prep_pack<<<dim3((476672 + 255) / 256), dim3(256), 0, stream>>>(
      q1w1, q1w1f, q1w2, q1w2f, q2w1, q2w1f, q2w2, q2w2f,
      mbw1, mbw1f, mbw2, mbw2f, mbw3, mbw3f);

  // ---- bottom-up: 4 launches (chain) ----
  const int up_base[4] = {7, 3, 1, 0};
  const int up_n[4]    = {8, 4, 2, 1};
  const int up_hc[4]   = {0, 1, 1, 1};
  for (int i = 0; i < 4; i++) {
    k_up<<<dim3(up_n[i] * (BN / 32)), dim3(256), 0, stream>>>(
        x, u, t_up1, up1b, t_up2, up2b, t_up3, up3b, msg_up, up_base[i], up_hc[i]);
  }

  // ---- mb chain: 3 launches (levels 0..2) ----
  const int mb_base[3] = {0, 1, 3};
  const int mb_n[3]    = {1, 2, 4};
  const int mb_hp[3]   = {0, 1, 1};
  for (int li = 0; li < 3; li++) {
    k_mb_mfma<<<dim3(mb_n[li] * (BN / 32)), dim3(512), 0, stream>>>(
        msg_up, msg_in, mbw1f, mbw2f, mbw3f, mbb1, mbb2, mbb3, msg_in, mb_base[li], mb_hp[li]);
  }

  // ---- Q: one launch over all 15 nodes, both nets ----
  k_q_mfma<<<dim3(15 * (BN / 64), 2), dim3(512), 0, stream>>>(
      msg_up, u, msg_in,
      q1w1f, q1w2f, q1w1, q1b1, q1b2, q1w3, q1b3,
      q2w1f, q2w2f, q2w1, q2b1, q2b2, q2w3, q2b3,
      out);
}